// Round 9
// baseline (362.621 us; speedup 1.0000x reference)
//
#include <hip/hip_runtime.h>
#include <stdint.h>

static constexpr int HIN = 256, WIN = 256, HO = 254, WOUT = 254, NB = 8;
static constexpr int PLANE = HO * WOUT;       // 64516
static constexpr int PIX = NB * PLANE;        // 516128

// ---------------------------------------------------------------------------
// Four specialized per-level kernels. Inter-level dependency is only the
// per-pixel allow mask; it is stashed as raw bit patterns inside `out` in a
// channel plane the CONSUMER kernel reads first and overwrites afterwards
// (same-stream launches => ordered). Stash planes: lvl0->ch8 (16b allow),
// lvl1->ch24 (32b), lvl2->ch56/ch57 (64b lo/hi). Every channel plane is
// fully rewritten by its owning level, so no stash survives.
//
// Numerics (validated rounds 0-1): patch px[27] with px[c*9+dy*3+dx] from
// source; per atom a single f32 accumulator from 0, sequential __fmaf_rn in
// (ky,kx,c) order over wp = w + atom*27 (t = c*9+ky*3+kx), bias added last
// as a separate __fadd_rn, gate applied after bias. Selection: jax top_k
// semantics — exactly K kept, boundary ties broken toward LOWEST index;
// m = K-th largest |act| with multiplicity via bitonic networks on the
// uint32 bit patterns of |act| (bit order == value order for |a| >= 0).
// ---------------------------------------------------------------------------

// Ring connectivity: prev atom j feeds next atoms (2j..2j+3) mod a_next.
__device__ __forceinline__ uint64_t spread_pairs(uint64_t mask, int a_next) {
  uint64_t s = mask;
  s = (s | (s << 16)) & 0x0000FFFF0000FFFFull;
  s = (s | (s << 8))  & 0x00FF00FF00FF00FFull;
  s = (s | (s << 4))  & 0x0F0F0F0F0F0F0F0Full;
  s = (s | (s << 2))  & 0x3333333333333333ull;
  s = (s | (s << 1))  & 0x5555555555555555ull;
  uint64_t pair = s | (s << 1);
  uint64_t lim = (a_next >= 64) ? ~0ull : ((1ull << a_next) - 1ull);
  uint64_t rot = ((pair << 2) | (pair >> (a_next - 2))) & lim;
  return (pair | rot) & lim;
}

// Bitonic sort (descending) of K uint32 in registers; fully unrolled, static
// indices, pure v_min_u32/v_max_u32 (round-1 validated).
template<int K>
__device__ __forceinline__ void bsort_desc(uint32_t (&v)[K]) {
#pragma unroll
  for (int sz = 2; sz <= K; sz <<= 1) {
#pragma unroll
    for (int st = sz >> 1; st > 0; st >>= 1) {
#pragma unroll
      for (int i = 0; i < K; ++i) {
        int l = i ^ st;
        if (l > i) {
          uint32_t a = v[i], c = v[l];
          uint32_t mx = a > c ? a : c;
          uint32_t mn = a > c ? c : a;
          bool desc = ((i & sz) == 0);
          v[i] = desc ? mx : mn;
          v[l] = desc ? mn : mx;
        }
      }
    }
  }
}

__device__ __forceinline__ void bmerge16(uint32_t (&v)[16]) {
#pragma unroll
  for (int st = 8; st > 0; st >>= 1) {
#pragma unroll
    for (int i = 0; i < 16; ++i) {
      int l = i ^ st;
      if (l > i) {
        uint32_t a = v[i], c = v[l];
        v[i] = a > c ? a : c;
        v[l] = a > c ? c : a;
      }
    }
  }
}

// Decompose pixel id and load the 3x3x3 patch into registers (round-0 form).
__device__ __forceinline__ void load_px(const float* __restrict__ x, int p,
                                        float (&px)[27], uint32_t& tofs4) {
  int bi = p / PLANE;
  int r  = p % PLANE;
  int h  = r / WOUT;
  int wc = r % WOUT;
  const float* xb = x + (size_t)bi * 3 * HIN * WIN;
#pragma unroll
  for (int c = 0; c < 3; ++c)
#pragma unroll
    for (int dy = 0; dy < 3; ++dy)
#pragma unroll
      for (int dx = 0; dx < 3; ++dx)
        px[c * 9 + dy * 3 + dx] =
            xb[c * HIN * WIN + (size_t)(h + dy) * WIN + (wc + dx)];
  tofs4 = (uint32_t)(bi * 120 * PLANE + r) * 4u;  // byte offset within out
}

// One atom's conv: validated (ky,kx,c)-ordered sequential FMA chain + bias.
__device__ __forceinline__ float conv_atom(const float (&px)[27],
                                           const float* __restrict__ wp,
                                           float bias) {
  float acc = 0.0f;
#pragma unroll
  for (int ky = 0; ky < 3; ++ky)
#pragma unroll
    for (int kx = 0; kx < 3; ++kx)
#pragma unroll
      for (int c = 0; c < 3; ++c) {
        int t = c * 9 + ky * 3 + kx;
        acc = __fmaf_rn(px[t], wp[t], acc);
      }
  return __fadd_rn(acc, bias);
}

// Keep + store + mask (validated ascending-j tie-break; quota in, msk out).
template<int N>
__device__ __forceinline__ uint64_t keep_store(const float (&act)[N], float m,
    int quota, char* __restrict__ outB, uint32_t tofs4, int ch0) {
  uint64_t msk = 0;
#pragma unroll
  for (int j = 0; j < N; ++j) {
    float aj = fabsf(act[j]);
    bool eq = (aj == m);
    bool keep = (aj > m) || (eq && quota > 0);
    quota -= eq ? 1 : 0;
    float v = keep ? act[j] : 0.0f;
    *(float*)(outB + (size_t)(ch0 + j) * PLANE * 4 + tofs4) = v;
    msk |= (v != 0.0f) ? (1ull << j) : 0ull;
  }
  return msk;
}

// ============================ level 0: N=8, K=2 ============================
__global__ __launch_bounds__(256, 8)
void lvl0(const float* __restrict__ x, const float* __restrict__ w,
          const float* __restrict__ b, float* __restrict__ out) {
  int p = blockIdx.x * blockDim.x + threadIdx.x;
  if (p >= PIX) return;
  float px[27]; uint32_t tofs4;
  load_px(x, p, px, tofs4);
  char* outB = (char*)out;

  float act[8];
#pragma unroll
  for (int j = 0; j < 8; ++j) act[j] = conv_atom(px, w + j * 27, b[j]);

  uint32_t v[8];
#pragma unroll
  for (int i = 0; i < 8; ++i) v[i] = __float_as_uint(act[i]) & 0x7fffffffu;
  bsort_desc<8>(v);
  uint32_t mb = v[1];                      // 2nd largest with multiplicity
  float m = __uint_as_float(mb);
  int base = 0;                            // #{|a| > m}
#pragma unroll
  for (int j = 0; j < 8; ++j) base += (fabsf(act[j]) > m) ? 1 : 0;
  int quota = 2 - base;

  uint64_t msk = keep_store<8>(act, m, quota, outB, tofs4, 0);
  uint32_t a1 = (uint32_t)spread_pairs(msk, 16);
  *(uint32_t*)(outB + (size_t)8 * PLANE * 4 + tofs4) = a1;   // stash -> ch8
}

// ============================ level 1: N=16, K=4 ===========================
__global__ __launch_bounds__(256, 6)
void lvl1(const float* __restrict__ x, const float* __restrict__ w,
          const float* __restrict__ b, float* __restrict__ out) {
  int p = blockIdx.x * blockDim.x + threadIdx.x;
  if (p >= PIX) return;
  float px[27]; uint32_t tofs4;
  load_px(x, p, px, tofs4);
  char* outB = (char*)out;
  uint32_t allow = *(const uint32_t*)(outB + (size_t)8 * PLANE * 4 + tofs4);

  float act[16];
#pragma unroll
  for (int j = 0; j < 16; ++j) {
    float a = conv_atom(px, w + (8 + j) * 27, b[8 + j]);
    act[j] = ((allow >> j) & 1u) ? a : 0.0f;
  }

  uint32_t v[16];
#pragma unroll
  for (int i = 0; i < 16; ++i) v[i] = __float_as_uint(act[i]) & 0x7fffffffu;
  bsort_desc<16>(v);
  uint32_t mb = v[3];                      // 4th largest with multiplicity
  float m = __uint_as_float(mb);
  int quota = 0;                           // #{i<4: v[i]==m}
#pragma unroll
  for (int i = 0; i < 4; ++i) quota += (v[i] == mb) ? 1 : 0;

  uint64_t msk = keep_store<16>(act, m, quota, outB, tofs4, 8);
  uint32_t a2 = (uint32_t)spread_pairs(msk, 32);
  *(uint32_t*)(outB + (size_t)24 * PLANE * 4 + tofs4) = a2;  // stash -> ch24
}

// ============================ level 2: N=32, K=8 ===========================
__global__ __launch_bounds__(256, 5)
void lvl2(const float* __restrict__ x, const float* __restrict__ w,
          const float* __restrict__ b, float* __restrict__ out) {
  int p = blockIdx.x * blockDim.x + threadIdx.x;
  if (p >= PIX) return;
  float px[27]; uint32_t tofs4;
  load_px(x, p, px, tofs4);
  char* outB = (char*)out;
  uint32_t allow = *(const uint32_t*)(outB + (size_t)24 * PLANE * 4 + tofs4);

  float act[32];
#pragma unroll
  for (int j = 0; j < 32; ++j) {
    float a = conv_atom(px, w + (24 + j) * 27, b[24 + j]);
    act[j] = ((allow >> j) & 1u) ? a : 0.0f;
  }

  uint32_t run[16], tmp[16];
#pragma unroll
  for (int i = 0; i < 16; ++i) run[i] = __float_as_uint(act[i]) & 0x7fffffffu;
#pragma unroll
  for (int i = 0; i < 16; ++i) tmp[i] = __float_as_uint(act[16 + i]) & 0x7fffffffu;
  bsort_desc<16>(run);
  bsort_desc<16>(tmp);
#pragma unroll
  for (int i = 0; i < 16; ++i) {          // top-16 of the two desc runs
    uint32_t c = tmp[15 - i];
    run[i] = run[i] > c ? run[i] : c;
  }
  bmerge16(run);                           // fully sorted top-16
  uint32_t mb = run[7];                    // 8th largest with multiplicity
  float m = __uint_as_float(mb);
  int quota = 0;                           // #{i<8: run[i]==m}
#pragma unroll
  for (int i = 0; i < 8; ++i) quota += (run[i] == mb) ? 1 : 0;

  uint64_t msk = keep_store<32>(act, m, quota, outB, tofs4, 24);
  uint64_t a3 = spread_pairs(msk, 64);
  *(uint32_t*)(outB + (size_t)56 * PLANE * 4 + tofs4) = (uint32_t)a3;        // lo
  *(uint32_t*)(outB + (size_t)57 * PLANE * 4 + tofs4) = (uint32_t)(a3 >> 32); // hi
}

// ============================ level 3: N=64, K=16 ==========================
__global__ __launch_bounds__(256, 4)
void lvl3(const float* __restrict__ x, const float* __restrict__ w,
          const float* __restrict__ b, float* __restrict__ out) {
  int p = blockIdx.x * blockDim.x + threadIdx.x;
  if (p >= PIX) return;
  float px[27]; uint32_t tofs4;
  load_px(x, p, px, tofs4);
  char* outB = (char*)out;
  uint32_t lo = *(const uint32_t*)(outB + (size_t)56 * PLANE * 4 + tofs4);
  uint32_t hi = *(const uint32_t*)(outB + (size_t)57 * PLANE * 4 + tofs4);
  uint64_t allow = (uint64_t)lo | ((uint64_t)hi << 32);

  float act[64];
#pragma unroll
  for (int j = 0; j < 64; ++j) {
    float a = conv_atom(px, w + (56 + j) * 27, b[56 + j]);
    act[j] = ((allow >> j) & 1ull) ? a : 0.0f;
  }

  // grouped bitonic top-16 of 64; run[] ends as the (unsorted) top-16
  // multiset — m = min16(run), quota = #{run[i]==m} (K=16 static).
  uint32_t run[16];
#pragma unroll
  for (int i = 0; i < 16; ++i) run[i] = __float_as_uint(act[i]) & 0x7fffffffu;
  bsort_desc<16>(run);
#pragma unroll
  for (int g = 1; g < 4; ++g) {
    uint32_t tmp[16];
#pragma unroll
    for (int i = 0; i < 16; ++i)
      tmp[i] = __float_as_uint(act[g * 16 + i]) & 0x7fffffffu;
    bsort_desc<16>(tmp);
#pragma unroll
    for (int i = 0; i < 16; ++i) {
      uint32_t c = tmp[15 - i];
      run[i] = run[i] > c ? run[i] : c;
    }
    if (g < 3) bmerge16(run);              // keep sorted for next merge only
  }
  uint32_t mb = run[0];
#pragma unroll
  for (int i = 1; i < 16; ++i) mb = mb < run[i] ? mb : run[i];
  float m = __uint_as_float(mb);
  int quota = 0;
#pragma unroll
  for (int i = 0; i < 16; ++i) quota += (run[i] == mb) ? 1 : 0;

  (void)keep_store<64>(act, m, quota, outB, tofs4, 56);
}

extern "C" void kernel_launch(void* const* d_in, const int* in_sizes, int n_in,
                              void* d_out, int out_size, void* d_ws, size_t ws_size,
                              hipStream_t stream) {
  const float* x = (const float*)d_in[0];
  const float* w = (const float*)d_in[1];
  const float* b = (const float*)d_in[2];
  float* out = (float*)d_out;
  dim3 blk(256), grid((PIX + 255) / 256);
  lvl0<<<grid, blk, 0, stream>>>(x, w, b, out);
  lvl1<<<grid, blk, 0, stream>>>(x, w, b, out);
  lvl2<<<grid, blk, 0, stream>>>(x, w, b, out);
  lvl3<<<grid, blk, 0, stream>>>(x, w, b, out);
}